// Round 6
// baseline (412.054 us; speedup 1.0000x reference)
//
#include <hip/hip_runtime.h>

#define IN_DIM  4096
#define OUT_DIM 1024
#define NN      4096
#define MM      8192
#define NSAMP   10

typedef __bf16 bf16x8 __attribute__((ext_vector_type(8)));
typedef float  fx4    __attribute__((ext_vector_type(4)));
typedef ushort u16x8  __attribute__((ext_vector_type(8)));

__device__ __forceinline__ ushort f2bf(float f) {
    union { float f; unsigned u; } v; v.f = f;
    unsigned u = v.u;
    return (ushort)((u + 0x7FFFu + ((u >> 16) & 1u)) >> 16);
}
__device__ __forceinline__ float bf2f(ushort u) {
    union { unsigned u; float f; } v; v.u = ((unsigned)u) << 16;
    return v.f;
}

// async global->LDS, 16B per lane; LDS dest = wave-uniform base + lane*16
#define GLDS(g, l) __builtin_amdgcn_global_load_lds(                           \
    (const __attribute__((address_space(1))) unsigned*)(g),                    \
    (__attribute__((address_space(3))) unsigned*)(l), 16, 0, 0)

// ---------------------------------------------------------------------------
// K1: v1[k] = sum_o a1[o]*W[o,k];  v2[k] = sum_o a2[o]*W[o,k]
//     + fused: Wbf = bf16(W)  (W read exactly once here)
// grid (16,64): x = k-tile of 256, y = o-slice of 16; atomicAdd partials.
// ---------------------------------------------------------------------------
__global__ __launch_bounds__(256) void k_attvec(const float* __restrict__ W,
                                                const float* __restrict__ att,
                                                float* __restrict__ v1,
                                                float* __restrict__ v2,
                                                ushort* __restrict__ Wbf) {
    int k  = blockIdx.x * 256 + threadIdx.x;
    int o0 = blockIdx.y * 16;
    float s1 = 0.f, s2 = 0.f;
#pragma unroll
    for (int o = o0; o < o0 + 16; ++o) {
        float w = W[(size_t)o * IN_DIM + k];
        Wbf[(size_t)o * IN_DIM + k] = f2bf(w);
        s1 += att[o] * w;
        s2 += att[OUT_DIM + o] * w;
    }
    atomicAdd(&v1[k], s1);
    atomicAdd(&v2[k], s2);
}

// ---------------------------------------------------------------------------
// K2: node rows only — nalpha[row] = node_f[row,:] . v1.
// (R6: neigh branch fused into k_gemm; Abf roundtrip eliminated.)
// One wave per row, 4 rows/block. v1 staged in LDS (removes half the global
// loads + their VGPRs); 8 independent float4 loads per pass, VGPR < 64
// (occupancy cliff at 64 per m69 — r5 lesson).
// ---------------------------------------------------------------------------
__global__ __launch_bounds__(256) void k_rows_node(const float* __restrict__ node_f,
                                                   const float* __restrict__ v1,
                                                   float* __restrict__ nalpha) {
    __shared__ __align__(16) float v1s[IN_DIM];   // 16 KB
#pragma unroll
    for (int i = 0; i < 4; ++i)
        *reinterpret_cast<float4*>(&v1s[threadIdx.x * 16 + i * 4]) =
            *reinterpret_cast<const float4*>(&v1[threadIdx.x * 16 + i * 4]);
    __syncthreads();

    int row  = blockIdx.x * 4 + (threadIdx.x >> 6);
    int lane = threadIdx.x & 63;
    const float4* xr = reinterpret_cast<const float4*>(node_f + (size_t)row * IN_DIM);
    const float4* vr = reinterpret_cast<const float4*>(v1s);
    float s = 0.f;
#pragma unroll
    for (int half = 0; half < 2; ++half) {
        float4 a[8];
#pragma unroll
        for (int i = 0; i < 8; ++i) a[i] = xr[lane + (half * 8 + i) * 64];
#pragma unroll
        for (int i = 0; i < 8; ++i) {
            float4 b = vr[lane + (half * 8 + i) * 64];
            s += a[i].x * b.x + a[i].y * b.y + a[i].z * b.z + a[i].w * b.w;
        }
    }
#pragma unroll
    for (int off = 32; off > 0; off >>= 1) s += __shfl_down(s, off, 64);
    if (lane == 0) nalpha[row] = s;
}

// ---------------------------------------------------------------------------
// K5: split-K x2 GEMM, A = neigh_f fp32 consumed DIRECTLY (r6):
//   reg-stage A: 8x float4 loads -> f2bf -> swizzled ds_write_b128 into As.
//   B (Wbf bf16) staged via GLDS exactly as before (proven path).
//   nbeta fusion: bn==0 blocks dot the staged fp32 A values against an
//   LDS-resident v2 slice (fp32, full accuracy) and atomicAdd per row.
// Structure otherwise identical to r5 (proven): 128x128 tile, 4 waves 2x2,
// BK=64, 2-barrier loop, default dim3(64,8,2) mapping (XCD = bx&7 -> each
// A panel read by ONE XCD; r3 lesson), conflict-free XOR chunk swizzle.
// Write-side swizzle: row r, global 16B-chunk g stored at p = g^(r&7);
// read side unchanged (expects exactly this layout). 8-lane ds_write groups
// hit 8 distinct chunks -> conflict-free.
// LDS: As 16KB + Bs 16KB + v2s 8KB = 40KB -> 4 blocks/CU.
// Fragment layouts (HW-verified, learn_hip m89):
//   A/B operand: outer = lane&15, k = (lane>>4)*8 + j  (k-step s adds s*32)
//   C/D:         col   = lane&15, row = (lane>>4)*4 + reg
// ---------------------------------------------------------------------------
#define TM 128
#define TN 128
#define BK 64
#define KSPLIT (IN_DIM / 2)

__global__ __launch_bounds__(256, 4) void k_gemm(const float* __restrict__ Af,
                                                 const ushort* __restrict__ B,
                                                 ushort* __restrict__ P,
                                                 const float* __restrict__ v2,
                                                 float* __restrict__ nbeta) {
    __shared__ __align__(16) ushort As[TM * BK];   // 16 KB
    __shared__ __align__(16) ushort Bs[TN * BK];   // 16 KB
    __shared__ __align__(16) float  v2s[KSPLIT];   // 8 KB
    const int tid  = threadIdx.x;
    const int lane = tid & 63;
    const int wave = tid >> 6;
    const int wm   = (wave >> 1) * 64;
    const int wn   = (wave & 1) * 64;
    const int lrow = lane & 15;
    const int q    = lane >> 4;

    const int bm  = blockIdx.x * TM;
    const int bn  = blockIdx.y * TN;
    const int bz  = blockIdx.z;
    const int kb  = bz * KSPLIT;

    // B staging (GLDS, unchanged): wave w rows w*32+(lane>>3)+8i, chunk lane&7,
    // source chunk pre-swizzled g=(lane&7)^(lane>>3).
    const int sr  = wave * 32 + (lane >> 3);
    const int sco = (((lane & 7) ^ (lane >> 3)) << 3);
    const ushort* gB = B + (size_t)(bn + sr) * IN_DIM + kb + sco;
    ushort* lB = Bs + wave * 2048;

    // A reg-staging: thread -> row r = tid>>1 (0..127), k-half h = tid&1.
    const int r = tid >> 1;
    const int h = tid & 1;
    const float* gA = Af + (size_t)(bm + r) * IN_DIM + kb + h * 32;
    ushort* wA = As + r * 64;

    // v2 slice -> LDS (for nbeta fusion; staged by all blocks, cheap)
#pragma unroll
    for (int i = 0; i < 2; ++i)
        *reinterpret_cast<float4*>(&v2s[tid * 8 + i * 4]) =
            *reinterpret_cast<const float4*>(&v2[kb + tid * 8 + i * 4]);
    __syncthreads();

    const int c0u = ((q ^ (lrow & 7)) << 3);
    const bool dofuse = (bn == 0);
    float sdot = 0.f;

    fx4 acc[4][4] = {};

    for (int k0 = 0; k0 < KSPLIT; k0 += BK) {
#pragma unroll
        for (int i = 0; i < 4; ++i)
            GLDS(gB + k0 + (size_t)i * 8 * IN_DIM, lB + i * 512);

        float4 a8[8];
#pragma unroll
        for (int l = 0; l < 8; ++l)
            a8[l] = *reinterpret_cast<const float4*>(gA + k0 + l * 4);

        if (dofuse) {
#pragma unroll
            for (int l = 0; l < 8; ++l) {
                float4 b = *reinterpret_cast<const float4*>(&v2s[k0 + h * 32 + l * 4]);
                sdot += a8[l].x * b.x + a8[l].y * b.y + a8[l].z * b.z + a8[l].w * b.w;
            }
        }

#pragma unroll
        for (int cc = 0; cc < 4; ++cc) {
            float4 u = a8[2 * cc], v = a8[2 * cc + 1];
            u16x8 o;
            o[0] = f2bf(u.x); o[1] = f2bf(u.y); o[2] = f2bf(u.z); o[3] = f2bf(u.w);
            o[4] = f2bf(v.x); o[5] = f2bf(v.y); o[6] = f2bf(v.z); o[7] = f2bf(v.w);
            const int p = ((h << 2) | cc) ^ (r & 7);
            *reinterpret_cast<u16x8*>(wA + p * 8) = o;
        }
        __syncthreads();

#pragma unroll
        for (int s = 0; s < 2; ++s) {
            const int co = c0u ^ (s << 5);
            bf16x8 af[4], bfr[4];
#pragma unroll
            for (int mi = 0; mi < 4; ++mi)
                af[mi] = *reinterpret_cast<const bf16x8*>(As + (wm + mi * 16 + lrow) * BK + co);
#pragma unroll
            for (int ni = 0; ni < 4; ++ni)
                bfr[ni] = *reinterpret_cast<const bf16x8*>(Bs + (wn + ni * 16 + lrow) * BK + co);
#pragma unroll
            for (int mi = 0; mi < 4; ++mi)
#pragma unroll
                for (int ni = 0; ni < 4; ++ni)
                    acc[mi][ni] = __builtin_amdgcn_mfma_f32_16x16x32_bf16(af[mi], bfr[ni], acc[mi][ni], 0, 0, 0);
        }
        __syncthreads();
    }

    if (dofuse) {
        sdot += __shfl_xor(sdot, 1, 64);       // pair (2r, 2r+1) shares row r
        if (h == 0) atomicAdd(&nbeta[bm + r], sdot);
    }

    ushort* Pz = P + (size_t)bz * MM * OUT_DIM;
#pragma unroll
    for (int mi = 0; mi < 4; ++mi)
#pragma unroll
        for (int ni = 0; ni < 4; ++ni) {
            int rr = bm + wm + mi * 16 + q * 4;
            int c  = bn + wn + ni * 16 + lrow;
#pragma unroll
            for (int v = 0; v < 4; ++v)
                Pz[(size_t)(rr + v) * OUT_DIM + c] = f2bf(acc[mi][ni][v]);
        }
}

// ---------------------------------------------------------------------------
// K6: parallel prologue — lanes 0..9 of wave 0 load idx/beta, dedupe via
// shfl (dup -> weight 0 == reference set semantics), softmax via shfl over
// 16 lanes.  Then all 256 threads gather: out = sum_t w_t*(P0[j_t]+P1[j_t]).
// ---------------------------------------------------------------------------
__global__ __launch_bounds__(256) void k_aggregate(const ushort* __restrict__ P,
                                                   const float* __restrict__ nalpha,
                                                   const float* __restrict__ nbeta,
                                                   const int* __restrict__ nidx,
                                                   float* __restrict__ outp) {
    int row = blockIdx.x;
    __shared__ int   s_idx[NSAMP];
    __shared__ float s_w[NSAMP];
    if (threadIdx.x < 16) {
        int t = threadIdx.x;
        int j = (t < NSAMP) ? nidx[row * NSAMP + t] : -1;
        float score = -INFINITY;
        if (t < NSAMP) {
            float x = nalpha[row] + nbeta[j];
            score = x > 0.f ? x : 0.2f * x;
        }
        bool dup = false;
#pragma unroll
        for (int sIdx = 0; sIdx < NSAMP; ++sIdx) {
            int js = __shfl(j, sIdx, 16);
            if (sIdx < t && js == j) dup = true;
        }
        float mx = score;
#pragma unroll
        for (int off = 8; off > 0; off >>= 1) {
            float o = __shfl_xor(mx, off, 16);
            mx = o > mx ? o : mx;
        }
        float e = (t < NSAMP && !dup) ? expf(score - mx) : 0.f;
        float sum = e;
#pragma unroll
        for (int off = 8; off > 0; off >>= 1) sum += __shfl_xor(sum, off, 16);
        if (t < NSAMP) {
            s_idx[t] = j;
            s_w[t]   = e / sum;
        }
    }
    __syncthreads();
    int col = threadIdx.x * 4;
    float ax = 0.f, ay = 0.f, az = 0.f, aw = 0.f;
#pragma unroll
    for (int t = 0; t < NSAMP; ++t) {
        float w = s_w[t];
        size_t off = (size_t)s_idx[t] * OUT_DIM + col;
        ushort4 u0 = *reinterpret_cast<const ushort4*>(P + off);
        ushort4 u1 = *reinterpret_cast<const ushort4*>(P + (size_t)MM * OUT_DIM + off);
        ax += w * (bf2f(u0.x) + bf2f(u1.x));
        ay += w * (bf2f(u0.y) + bf2f(u1.y));
        az += w * (bf2f(u0.z) + bf2f(u1.z));
        aw += w * (bf2f(u0.w) + bf2f(u1.w));
    }
    float4 o; o.x = ax; o.y = ay; o.z = az; o.w = aw;
    *reinterpret_cast<float4*>(outp + (size_t)row * OUT_DIM + col) = o;
}

// ---------------------------------------------------------------------------
extern "C" void kernel_launch(void* const* d_in, const int* in_sizes, int n_in,
                              void* d_out, int out_size, void* d_ws, size_t ws_size,
                              hipStream_t stream) {
    const float* node_f  = (const float*)d_in[0];  // 4096 x 4096
    const float* neigh_f = (const float*)d_in[1];  // 8192 x 4096
    const float* W       = (const float*)d_in[2];  // 1024 x 4096
    const float* att     = (const float*)d_in[3];  // 2048
    const int*   nidx    = (const int*)d_in[4];    // 4096 x 10
    float* outp = (float*)d_out;                   // 4096 x 1024 fp32

    char* ws = (char*)d_ws;
    ushort* Wbf = (ushort*)ws;                     // 8 MB bf16 W
    ushort* P   = (ushort*)(ws + 8388608);         // 2 x 16 MB bf16 partials
    float*  v1     = (float*)(ws + 41943040);
    float*  v2     = v1 + IN_DIM;
    float*  nbeta  = v2 + IN_DIM;                  // zeroed (gemm atomics)
    float*  nalpha = nbeta + MM;

    // zero v1, v2, nbeta (contiguous): (4096+4096+8192)*4 = 64 KiB
    hipMemsetAsync(v1, 0, (2 * IN_DIM + MM) * sizeof(float), stream);

    k_attvec   <<<dim3(16, 64),   256, 0, stream>>>(W, att, v1, v2, Wbf);
    k_gemm     <<<dim3(64, 8, 2), 256, 0, stream>>>(neigh_f, Wbf, P, v2, nbeta);
    k_rows_node<<<NN / 4,         256, 0, stream>>>(node_f, v1, nalpha);
    k_aggregate<<<NN,             256, 0, stream>>>(P, nalpha, nbeta, nidx, outp);
}

// Round 7
// 369.115 us; speedup vs baseline: 1.1163x; 1.1163x over previous
//
#include <hip/hip_runtime.h>

#define IN_DIM  4096
#define OUT_DIM 1024
#define NN      4096
#define MM      8192
#define NSAMP   10

typedef __bf16 bf16x8 __attribute__((ext_vector_type(8)));
typedef float  fx4    __attribute__((ext_vector_type(4)));

__device__ __forceinline__ ushort f2bf(float f) {
    union { float f; unsigned u; } v; v.f = f;
    unsigned u = v.u;
    return (ushort)((u + 0x7FFFu + ((u >> 16) & 1u)) >> 16);
}
__device__ __forceinline__ float bf2f(ushort u) {
    union { unsigned u; float f; } v; v.u = ((unsigned)u) << 16;
    return v.f;
}

// async global->LDS, 16B per lane; LDS dest = wave-uniform base + lane*16
#define GLDS(g, l) __builtin_amdgcn_global_load_lds(                           \
    (const __attribute__((address_space(1))) unsigned*)(g),                    \
    (__attribute__((address_space(3))) unsigned*)(l), 16, 0, 0)

// ---------------------------------------------------------------------------
// K1: v1[k] = sum_o a1[o]*W[o,k];  v2[k] = sum_o a2[o]*W[o,k]
//     + fused: Wbf = bf16(W)  (W read exactly once here)
// grid (16,64): x = k-tile of 256, y = o-slice of 16; atomicAdd partials.
// ---------------------------------------------------------------------------
__global__ __launch_bounds__(256) void k_attvec(const float* __restrict__ W,
                                                const float* __restrict__ att,
                                                float* __restrict__ v1,
                                                float* __restrict__ v2,
                                                ushort* __restrict__ Wbf) {
    int k  = blockIdx.x * 256 + threadIdx.x;
    int o0 = blockIdx.y * 16;
    float s1 = 0.f, s2 = 0.f;
#pragma unroll
    for (int o = o0; o < o0 + 16; ++o) {
        float w = W[(size_t)o * IN_DIM + k];
        Wbf[(size_t)o * IN_DIM + k] = f2bf(w);
        s1 += att[o] * w;
        s2 += att[OUT_DIM + o] * w;
    }
    atomicAdd(&v1[k], s1);
    atomicAdd(&v2[k], s2);
}

// ---------------------------------------------------------------------------
// K2: one WAVE per row over NN + MM rows (4 rows per 256-thr block).
//   row < NN:  nalpha[row] = node_f[row,:] . v1
//   row >= NN: j = row-NN;  nbeta[j] = neigh_f[j,:] . v2  AND Abf[j,:] = bf16
// R7: the untested occupancy x ILP cell. r4 (VGPR12, occ 62%, ILP 1) and
// r5 (VGPR64 = cliff, occ 34%, ILP 8) both gave ~2.8 TB/s effective.
// Here: 4 segments x 8 independent float4 loads, `#pragma unroll 1` pins
// VGPR ~44 (below the 64 cliff, m69) -> occ ~60% AND 8 loads in flight.
// ---------------------------------------------------------------------------
__global__ __launch_bounds__(256) void k_rows(const float* __restrict__ node_f,
                                              const float* __restrict__ neigh_f,
                                              const float* __restrict__ v1,
                                              const float* __restrict__ v2,
                                              float* __restrict__ nalpha,
                                              float* __restrict__ nbeta,
                                              ushort* __restrict__ Abf) {
    int row  = blockIdx.x * 4 + (threadIdx.x >> 6);
    int lane = threadIdx.x & 63;
    float s = 0.f;
    if (row < NN) {
        const float4* xr = reinterpret_cast<const float4*>(node_f + (size_t)row * IN_DIM);
        const float4* vr = reinterpret_cast<const float4*>(v1);
#pragma unroll 1
        for (int it = 0; it < 4; ++it) {
            int base = lane + it * 256;
            float4 a0 = xr[base], a1 = xr[base + 64], a2 = xr[base + 128], a3 = xr[base + 192];
            float4 b0 = vr[base], b1 = vr[base + 64], b2 = vr[base + 128], b3 = vr[base + 192];
            s += a0.x * b0.x + a0.y * b0.y + a0.z * b0.z + a0.w * b0.w;
            s += a1.x * b1.x + a1.y * b1.y + a1.z * b1.z + a1.w * b1.w;
            s += a2.x * b2.x + a2.y * b2.y + a2.z * b2.z + a2.w * b2.w;
            s += a3.x * b3.x + a3.y * b3.y + a3.z * b3.z + a3.w * b3.w;
        }
    } else {
        int j = row - NN;
        const float4* xr = reinterpret_cast<const float4*>(neigh_f + (size_t)j * IN_DIM);
        const float4* vr = reinterpret_cast<const float4*>(v2);
        ushort4* yr = reinterpret_cast<ushort4*>(Abf + (size_t)j * IN_DIM);
#pragma unroll 1
        for (int it = 0; it < 4; ++it) {
            int base = lane + it * 256;
            float4 a0 = xr[base], a1 = xr[base + 64], a2 = xr[base + 128], a3 = xr[base + 192];
            float4 b0 = vr[base], b1 = vr[base + 64], b2 = vr[base + 128], b3 = vr[base + 192];
            s += a0.x * b0.x + a0.y * b0.y + a0.z * b0.z + a0.w * b0.w;
            s += a1.x * b1.x + a1.y * b1.y + a1.z * b1.z + a1.w * b1.w;
            s += a2.x * b2.x + a2.y * b2.y + a2.z * b2.z + a2.w * b2.w;
            s += a3.x * b3.x + a3.y * b3.y + a3.z * b3.z + a3.w * b3.w;
            ushort4 o0, o1, o2, o3;
            o0.x = f2bf(a0.x); o0.y = f2bf(a0.y); o0.z = f2bf(a0.z); o0.w = f2bf(a0.w);
            o1.x = f2bf(a1.x); o1.y = f2bf(a1.y); o1.z = f2bf(a1.z); o1.w = f2bf(a1.w);
            o2.x = f2bf(a2.x); o2.y = f2bf(a2.y); o2.z = f2bf(a2.z); o2.w = f2bf(a2.w);
            o3.x = f2bf(a3.x); o3.y = f2bf(a3.y); o3.z = f2bf(a3.z); o3.w = f2bf(a3.w);
            yr[base]       = o0;
            yr[base + 64]  = o1;
            yr[base + 128] = o2;
            yr[base + 192] = o3;
        }
    }
#pragma unroll
    for (int off = 32; off > 0; off >>= 1) s += __shfl_down(s, off, 64);
    if (lane == 0) {
        if (row < NN) nalpha[row] = s; else nbeta[row - NN] = s;
    }
}

// ---------------------------------------------------------------------------
// K5: split-K x2 GEMM — r5 proven version, verbatim. 128x128 tile, 4 waves
// 2x2 of 64x64, BK=64, GLDS both operands, conflict-free XOR chunk swizzle,
// DEFAULT dim3(64,8,2) mapping (XCD = bx&7 -> each A panel read by ONE XCD;
// r3/r6 lessons: do NOT invert the mapping, do NOT reg-stage A).
// Fragment layouts (HW-verified, learn_hip m89):
//   A/B operand: outer = lane&15, k = (lane>>4)*8 + j  (k-step s adds s*32)
//   C/D:         col   = lane&15, row = (lane>>4)*4 + reg
// ---------------------------------------------------------------------------
#define TM 128
#define TN 128
#define BK 64
#define KSPLIT (IN_DIM / 2)

__global__ __launch_bounds__(256, 4) void k_gemm(const ushort* __restrict__ A,
                                                 const ushort* __restrict__ B,
                                                 ushort* __restrict__ P) {
    __shared__ __align__(16) ushort As[TM * BK];   // 16 KB
    __shared__ __align__(16) ushort Bs[TN * BK];   // 16 KB
    const int tid  = threadIdx.x;
    const int lane = tid & 63;
    const int wave = tid >> 6;
    const int wm   = (wave >> 1) * 64;
    const int wn   = (wave & 1) * 64;
    const int lrow = lane & 15;
    const int q    = lane >> 4;

    const int bm  = blockIdx.x * TM;
    const int bn  = blockIdx.y * TN;
    const int bz  = blockIdx.z;
    const int kb  = bz * KSPLIT;

    // staging: wave w covers rows w*32 + (lane>>3) + 8i, chunk lane&7.
    // source chunk pre-swizzled: g = (lane&7) ^ (sr&7), sr&7 == lane>>3.
    const int sr  = wave * 32 + (lane >> 3);
    const int sco = (((lane & 7) ^ (lane >> 3)) << 3);   // ushort offset
    const ushort* gA = A + (size_t)(bm + sr) * IN_DIM + kb + sco;
    const ushort* gB = B + (size_t)(bn + sr) * IN_DIM + kb + sco;
    ushort* lA = As + wave * 2048;
    ushort* lB = Bs + wave * 2048;

    // read-side swizzled chunk offset (ushorts): step s flips bit2 (^32)
    const int c0u = ((q ^ (lrow & 7)) << 3);

    fx4 acc[4][4] = {};

    for (int k0 = 0; k0 < KSPLIT; k0 += BK) {
#pragma unroll
        for (int i = 0; i < 4; ++i)
            GLDS(gA + k0 + (size_t)i * 8 * IN_DIM, lA + i * 512);
#pragma unroll
        for (int i = 0; i < 4; ++i)
            GLDS(gB + k0 + (size_t)i * 8 * IN_DIM, lB + i * 512);
        __syncthreads();

#pragma unroll
        for (int s = 0; s < 2; ++s) {
            const int co = c0u ^ (s << 5);
            bf16x8 af[4], bfr[4];
#pragma unroll
            for (int mi = 0; mi < 4; ++mi)
                af[mi] = *reinterpret_cast<const bf16x8*>(As + (wm + mi * 16 + lrow) * BK + co);
#pragma unroll
            for (int ni = 0; ni < 4; ++ni)
                bfr[ni] = *reinterpret_cast<const bf16x8*>(Bs + (wn + ni * 16 + lrow) * BK + co);
#pragma unroll
            for (int mi = 0; mi < 4; ++mi)
#pragma unroll
                for (int ni = 0; ni < 4; ++ni)
                    acc[mi][ni] = __builtin_amdgcn_mfma_f32_16x16x32_bf16(af[mi], bfr[ni], acc[mi][ni], 0, 0, 0);
        }
        __syncthreads();
    }

    ushort* Pz = P + (size_t)bz * MM * OUT_DIM;
#pragma unroll
    for (int mi = 0; mi < 4; ++mi)
#pragma unroll
        for (int ni = 0; ni < 4; ++ni) {
            int r = bm + wm + mi * 16 + q * 4;
            int c = bn + wn + ni * 16 + lrow;
#pragma unroll
            for (int v = 0; v < 4; ++v)
                Pz[(size_t)(r + v) * OUT_DIM + c] = f2bf(acc[mi][ni][v]);
        }
}

// ---------------------------------------------------------------------------
// K6: parallel prologue — lanes 0..15 of wave 0 compute softmax weights via
// shfl (dup -> weight 0 == reference set semantics).  Gather phase (R7):
// BATCHED — 2 batches of 5 samples x 2 halves = 10 independent loads in
// flight (was 10 sequential dependent iterations = 10 exposed latencies).
// ---------------------------------------------------------------------------
__global__ __launch_bounds__(256) void k_aggregate(const ushort* __restrict__ P,
                                                   const float* __restrict__ nalpha,
                                                   const float* __restrict__ nbeta,
                                                   const int* __restrict__ nidx,
                                                   float* __restrict__ outp) {
    int row = blockIdx.x;
    __shared__ int   s_idx[NSAMP];
    __shared__ float s_w[NSAMP];
    if (threadIdx.x < 16) {
        int t = threadIdx.x;
        int j = (t < NSAMP) ? nidx[row * NSAMP + t] : -1;
        float score = -INFINITY;
        if (t < NSAMP) {
            float x = nalpha[row] + nbeta[j];
            score = x > 0.f ? x : 0.2f * x;
        }
        bool dup = false;
#pragma unroll
        for (int sIdx = 0; sIdx < NSAMP; ++sIdx) {
            int js = __shfl(j, sIdx, 16);
            if (sIdx < t && js == j) dup = true;
        }
        float mx = score;
#pragma unroll
        for (int off = 8; off > 0; off >>= 1) {
            float o = __shfl_xor(mx, off, 16);
            mx = o > mx ? o : mx;
        }
        float e = (t < NSAMP && !dup) ? expf(score - mx) : 0.f;
        float sum = e;
#pragma unroll
        for (int off = 8; off > 0; off >>= 1) sum += __shfl_xor(sum, off, 16);
        if (t < NSAMP) {
            s_idx[t] = j;
            s_w[t]   = e / sum;
        }
    }
    __syncthreads();
    int col = threadIdx.x * 4;
    const ushort* P1 = P + (size_t)MM * OUT_DIM;
    float ax = 0.f, ay = 0.f, az = 0.f, aw = 0.f;
#pragma unroll
    for (int b = 0; b < 2; ++b) {
        ushort4 u0[5], u1[5];
        float   w[5];
#pragma unroll
        for (int t = 0; t < 5; ++t) {
            size_t off = (size_t)s_idx[b * 5 + t] * OUT_DIM + col;
            u0[t] = *reinterpret_cast<const ushort4*>(P + off);
            u1[t] = *reinterpret_cast<const ushort4*>(P1 + off);
            w[t]  = s_w[b * 5 + t];
        }
#pragma unroll
        for (int t = 0; t < 5; ++t) {
            ax += w[t] * (bf2f(u0[t].x) + bf2f(u1[t].x));
            ay += w[t] * (bf2f(u0[t].y) + bf2f(u1[t].y));
            az += w[t] * (bf2f(u0[t].z) + bf2f(u1[t].z));
            aw += w[t] * (bf2f(u0[t].w) + bf2f(u1[t].w));
        }
    }
    float4 o; o.x = ax; o.y = ay; o.z = az; o.w = aw;
    *reinterpret_cast<float4*>(outp + (size_t)row * OUT_DIM + col) = o;
}

// ---------------------------------------------------------------------------
extern "C" void kernel_launch(void* const* d_in, const int* in_sizes, int n_in,
                              void* d_out, int out_size, void* d_ws, size_t ws_size,
                              hipStream_t stream) {
    const float* node_f  = (const float*)d_in[0];  // 4096 x 4096
    const float* neigh_f = (const float*)d_in[1];  // 8192 x 4096
    const float* W       = (const float*)d_in[2];  // 1024 x 4096
    const float* att     = (const float*)d_in[3];  // 2048
    const int*   nidx    = (const int*)d_in[4];    // 4096 x 10
    float* outp = (float*)d_out;                   // 4096 x 1024 fp32

    char* ws = (char*)d_ws;
    ushort* Abf = (ushort*)ws;                     // 64 MB bf16 A
    ushort* Wbf = (ushort*)(ws + 67108864);        // 8 MB  bf16 W
    ushort* P   = (ushort*)(ws + 75497472);        // 2 x 16 MB bf16 partials
    float*  v1     = (float*)(ws + 109051904);
    float*  v2     = v1 + IN_DIM;
    float*  nalpha = v2 + IN_DIM;
    float*  nbeta  = nalpha + NN;

    hipMemsetAsync(v1, 0, 2 * IN_DIM * sizeof(float), stream);

    k_attvec   <<<dim3(16, 64),   256, 0, stream>>>(W, att, v1, v2, Wbf);
    k_rows     <<<(NN + MM) / 4,  256, 0, stream>>>(node_f, neigh_f, v1, v2, nalpha, nbeta, Abf);
    k_gemm     <<<dim3(64, 8, 2), 256, 0, stream>>>(Abf, Wbf, P);
    k_aggregate<<<NN,             256, 0, stream>>>(P, nalpha, nbeta, nidx, outp);
}